// Round 1
// baseline (164.148 us; speedup 1.0000x reference)
//
#include <hip/hip_runtime.h>
#include <hip/hip_bf16.h>

// DeconvCapsuleLayer fused kernel: conv2d_transpose (votes) via bf16 MFMA +
// 3-iteration dynamic routing, all in registers, one wave = 2 output positions.
//
// Shapes: in [8,56,56,8,32] f32, W [4,4,64,32] f32 (kh,kw,out,in), b [4,16],
// out [8,112,112,4,16] f32.
//
// Conv-transpose (stride 2, K=4, SAME -> pad 1): output o uses taps
//   o even: k in {1,3}, i = o/2 - ty      (ky = 2*ty+1)
//   o odd : k in {0,2}, i = (o+1)/2 - ty  (ky = 2*ty)
// i.e. with o = 2*y+py: ky = 2*ty + (py^1), iy = y + py - ty, valid iff 0<=iy<56.

typedef __attribute__((ext_vector_type(8))) short bf16x8;
typedef __attribute__((ext_vector_type(4))) float f32x4;

static __device__ __forceinline__ short f2bf(float f) {
    union { __hip_bfloat16 h; unsigned short u; } cv;
    cv.h = __float2bfloat16(f);  // RNE
    return (short)cv.u;
}

__global__ __launch_bounds__(256, 2)
void caps_deconv_route(const float* __restrict__ in, const float* __restrict__ Wt,
                       const float* __restrict__ bia, float* __restrict__ out) {
    const int tid  = threadIdx.x;
    const int lane = tid & 63;
    const int wid  = tid >> 6;
    const int bid  = blockIdx.x;

    // grid = 8 batches x 4 parity classes x 49 tiles
    const int tile = bid % 49;
    const int cls  = (bid / 49) & 3;
    const int b    = bid / 196;
    const int py = cls >> 1, px = cls & 1;

    const int col  = lane & 15;   // N-col within 16-tile / oa
    const int koct = lane >> 4;   // k-octet 0..3

    // ---- B fragments (weights for this parity class), held in VGPRs ----
    // B[k][ch], k = (ty*2+tx)*32 + ci, ch = oc*16+oa
    bf16x8 bf[4][4];
    #pragma unroll
    for (int s = 0; s < 4; ++s) {
        const int ty = s >> 1, tx = s & 1;
        const int ky = 2*ty + (py ^ 1);
        const int kx = 2*tx + (px ^ 1);
        #pragma unroll
        for (int nt = 0; nt < 4; ++nt) {
            const int ch = nt*16 + col;
            const float* wp = Wt + (((ky*4 + kx)*64 + ch)*32 + koct*8);
            const float4 w0 = *(const float4*)(wp);
            const float4 w1 = *(const float4*)(wp + 4);
            bf16x8 v;
            v[0]=f2bf(w0.x); v[1]=f2bf(w0.y); v[2]=f2bf(w0.z); v[3]=f2bf(w0.w);
            v[4]=f2bf(w1.x); v[5]=f2bf(w1.y); v[6]=f2bf(w1.z); v[7]=f2bf(w1.w);
            bf[s][nt] = v;
        }
    }

    const int oa = col;
    float bias_v[4];
    #pragma unroll
    for (int oc = 0; oc < 4; ++oc) bias_v[oc] = bia[oc*16 + oa];

    const int posl  = lane >> 5;        // C rows: which position of the pair
    const int ich   = (lane >> 4) & 1;  // C rows: ic half (rows = ich*4+q)
    const int a_pos = (lane >> 3) & 1;  // A row bit3 -> position
    const int a_ic  = lane & 7;         // A row bits0-2 -> ic

    for (int i = 0; i < 8; ++i) {
        const int pid = tile*32 + wid*8 + i;     // pair index within class
        const int p0  = pid * 2;
        const int y   = p0 / 56;
        const int x0  = p0 - y*56;               // 56 even -> pair shares row

        // ---- A fragments: A[r][k], r = pos*8+ic, k = s*32+ci ----
        bf16x8 af[4];
        const int ax = x0 + a_pos;
        #pragma unroll
        for (int s = 0; s < 4; ++s) {
            const int ty = s >> 1, tx = s & 1;
            const int iy = y + py - ty;
            const int ix = ax + px - tx;
            float4 a0 = make_float4(0.f, 0.f, 0.f, 0.f);
            float4 a1 = make_float4(0.f, 0.f, 0.f, 0.f);
            if ((unsigned)iy < 56u && (unsigned)ix < 56u) {
                const float* ap = in + ((((b*56 + iy)*56 + ix)*8 + a_ic)*32 + koct*8);
                a0 = *(const float4*)(ap);
                a1 = *(const float4*)(ap + 4);
            }
            bf16x8 v;
            v[0]=f2bf(a0.x); v[1]=f2bf(a0.y); v[2]=f2bf(a0.z); v[3]=f2bf(a0.w);
            v[4]=f2bf(a1.x); v[5]=f2bf(a1.y); v[6]=f2bf(a1.z); v[7]=f2bf(a1.w);
            af[s] = v;
        }

        // ---- votes: C[16][64] = A*B, acc[nt] holds N-tile nt ----
        f32x4 acc[4];
        #pragma unroll
        for (int nt = 0; nt < 4; ++nt) {
            acc[nt][0]=0.f; acc[nt][1]=0.f; acc[nt][2]=0.f; acc[nt][3]=0.f;
        }
        #pragma unroll
        for (int s = 0; s < 4; ++s)
            #pragma unroll
            for (int nt = 0; nt < 4; ++nt)
                acc[nt] = __builtin_amdgcn_mfma_f32_16x16x32_bf16(af[s], bf[s][nt], acc[nt], 0, 0, 0);

        // lane holds votes[ic = ich*4+q][oc = nt][oa] for pos = posl:
        //   votes = acc[oc][q]

        // ---- dynamic routing, 3 iterations, in registers ----
        float logit[4][4] = {{0,0,0,0},{0,0,0,0},{0,0,0,0},{0,0,0,0}};
        float act[4];
        #pragma unroll
        for (int it = 0; it < 3; ++it) {
            // softmax over oc for each of this lane's 4 ic rows
            float route[4][4];
            #pragma unroll
            for (int q = 0; q < 4; ++q) {
                float m = fmaxf(fmaxf(logit[q][0], logit[q][1]),
                                fmaxf(logit[q][2], logit[q][3]));
                float ssum = 0.f;
                #pragma unroll
                for (int oc = 0; oc < 4; ++oc) {
                    float e = __expf(logit[q][oc] - m);
                    route[q][oc] = e; ssum += e;
                }
                float inv = __builtin_amdgcn_rcpf(ssum);
                #pragma unroll
                for (int oc = 0; oc < 4; ++oc) route[q][oc] *= inv;
            }
            // preact[oc] = sum_ic route*votes  (+xor16 joins the two ic halves) + bias
            #pragma unroll
            for (int oc = 0; oc < 4; ++oc) {
                float p = route[0][oc]*acc[oc][0] + route[1][oc]*acc[oc][1]
                        + route[2][oc]*acc[oc][2] + route[3][oc]*acc[oc][3];
                p += __shfl_xor(p, 16, 64);
                p += bias_v[oc];
                // squash: norm over 16 oa lanes
                float sq = p * p;
                sq += __shfl_xor(sq, 1, 64);
                sq += __shfl_xor(sq, 2, 64);
                sq += __shfl_xor(sq, 4, 64);
                sq += __shfl_xor(sq, 8, 64);
                act[oc] = p * (sqrtf(sq) * __builtin_amdgcn_rcpf(1.f + sq));
            }
            // logits += sum_oa votes*act (skip on last iter)
            if (it < 2) {
                #pragma unroll
                for (int q = 0; q < 4; ++q)
                    #pragma unroll
                    for (int oc = 0; oc < 4; ++oc) {
                        float c = acc[oc][q] * act[oc];
                        c += __shfl_xor(c, 1, 64);
                        c += __shfl_xor(c, 2, 64);
                        c += __shfl_xor(c, 4, 64);
                        c += __shfl_xor(c, 8, 64);
                        logit[q][oc] += c;
                    }
            }
        }

        // ---- store activation (lanes with ich==0 carry each position once) ----
        if (ich == 0) {
            const int oy = 2*y + py;
            const int ox = 2*(x0 + posl) + px;
            float* op = out + (((b*112 + oy)*112 + ox)*64 + oa);
            #pragma unroll
            for (int oc = 0; oc < 4; ++oc) op[oc*16] = act[oc];
        }
    }
}

extern "C" void kernel_launch(void* const* d_in, const int* in_sizes, int n_in,
                              void* d_out, int out_size, void* d_ws, size_t ws_size,
                              hipStream_t stream) {
    const float* in  = (const float*)d_in[0];
    const float* Wt  = (const float*)d_in[1];
    const float* bia = (const float*)d_in[2];
    float* out = (float*)d_out;
    hipLaunchKernelGGL(caps_deconv_route, dim3(1568), dim3(256), 0, stream,
                       in, Wt, bia, out);
}

// Round 2
// 109.301 us; speedup vs baseline: 1.5018x; 1.5018x over previous
//
#include <hip/hip_runtime.h>
#include <hip/hip_bf16.h>

// DeconvCapsuleLayer fused kernel, round 2.
// conv2d_transpose (votes) via bf16 MFMA + 3-iter dynamic routing in registers.
// Round-2 changes vs round 1:
//   - weights staged in LDS (16 KB/block, shared by all 4 waves) instead of
//     64 persistent VGPRs -> higher occupancy
//   - all 16-lane (oa-group) reductions via DPP (quad_perm/row_mirror) instead
//     of ds_swizzle shuffles -> DS ops per pair ~188 -> ~12
//   - routing iteration 1 folded (route == 0.25 exactly)
//
// Conv-transpose (stride 2, K=4, SAME -> pad 1): with o = 2*y+py:
//   ky = 2*ty + (py^1), iy = y + py - ty, valid iff 0<=iy<56 (same for x).

typedef __attribute__((ext_vector_type(8))) short bf16x8;
typedef __attribute__((ext_vector_type(4))) float f32x4;

static __device__ __forceinline__ unsigned short f2bfu(float f) {
    union { __hip_bfloat16 h; unsigned short u; } cv;
    cv.h = __float2bfloat16(f);  // RNE
    return cv.u;
}
static __device__ __forceinline__ short f2bf(float f) { return (short)f2bfu(f); }

// Sum across each 16-lane row (oa group), result broadcast to all 16 lanes.
// Stages: xor1 (quad_perm [1,0,3,2]), xor2 (quad_perm [2,3,0,1]),
// cross-quad (row_half_mirror), cross-half (row_mirror). All DPP = VALU-rate.
static __device__ __forceinline__ float dpp_sum16(float v) {
    int x;
    x = __builtin_bit_cast(int, v);
    v += __builtin_bit_cast(float, __builtin_amdgcn_mov_dpp(x, 0xB1, 0xF, 0xF, true));
    x = __builtin_bit_cast(int, v);
    v += __builtin_bit_cast(float, __builtin_amdgcn_mov_dpp(x, 0x4E, 0xF, 0xF, true));
    x = __builtin_bit_cast(int, v);
    v += __builtin_bit_cast(float, __builtin_amdgcn_mov_dpp(x, 0x141, 0xF, 0xF, true));
    x = __builtin_bit_cast(int, v);
    v += __builtin_bit_cast(float, __builtin_amdgcn_mov_dpp(x, 0x140, 0xF, 0xF, true));
    return v;
}

__global__ __launch_bounds__(256, 4)
void caps_deconv_route(const float* __restrict__ in, const float* __restrict__ Wt,
                       const float* __restrict__ bia, float* __restrict__ out) {
    const int tid  = threadIdx.x;
    const int lane = tid & 63;
    const int wid  = tid >> 6;
    const int bid  = blockIdx.x;

    // grid = 8 batches x 4 parity classes x 49 tiles
    const int tile = bid % 49;
    const int cls  = (bid / 49) & 3;
    const int b    = bid / 196;
    const int py = cls >> 1, px = cls & 1;

    // ---- stage weights (this parity class) into LDS as bf16 B-fragments ----
    // LDS image: uint4[(s*4 + koct)*64 + ch], ch = oc*16+oa; each uint4 = 8 bf16
    // = W[ky(s)][kx(s)][ch][ci = koct*8 .. +7]
    __shared__ uint4 wlds[1024];  // 16 KB
    for (int t = tid; t < 1024; t += 256) {
        const int s    = t >> 8;
        const int koct = (t >> 6) & 3;
        const int ch   = t & 63;
        const int ky = 2*(s >> 1) + (py ^ 1);
        const int kx = 2*(s & 1)  + (px ^ 1);
        const float* wp = Wt + (((ky*4 + kx)*64 + ch)*32 + koct*8);
        const float4 w0 = *(const float4*)(wp);
        const float4 w1 = *(const float4*)(wp + 4);
        uint4 u;
        u.x = ((unsigned)f2bfu(w0.y) << 16) | f2bfu(w0.x);
        u.y = ((unsigned)f2bfu(w0.w) << 16) | f2bfu(w0.z);
        u.z = ((unsigned)f2bfu(w1.y) << 16) | f2bfu(w1.x);
        u.w = ((unsigned)f2bfu(w1.w) << 16) | f2bfu(w1.z);
        wlds[t] = u;
    }
    __syncthreads();

    const int col  = lane & 15;   // oa / N-col within 16-tile
    const int koct = lane >> 4;   // k-octet 0..3
    const int wbase = koct*64 + col;   // LDS frag index = wbase + s*256 + nt*16

    const int oa = col;
    float bias_v[4];
    #pragma unroll
    for (int oc = 0; oc < 4; ++oc) bias_v[oc] = bia[oc*16 + oa];

    const int posl  = lane >> 5;        // C rows: which position of the pair
    const int ich   = (lane >> 4) & 1;  // C rows: ic half (rows = ich*4+q)
    const int a_pos = (lane >> 3) & 1;  // A row bit3 -> position
    const int a_ic  = lane & 7;         // A row bits0-2 -> ic

    for (int i = 0; i < 8; ++i) {
        const int pid = tile*32 + wid*8 + i;     // pair index within class
        const int p0  = pid * 2;
        const int y   = p0 / 56;
        const int x0  = p0 - y*56;               // 56 even -> pair shares row

        // ---- A fragments: A[r][k], r = pos*8+ic, k = s*32+ci ----
        bf16x8 af[4];
        const int ax = x0 + a_pos;
        #pragma unroll
        for (int s = 0; s < 4; ++s) {
            const int ty = s >> 1, tx = s & 1;
            const int iy = y + py - ty;
            const int ix = ax + px - tx;
            float4 a0 = make_float4(0.f, 0.f, 0.f, 0.f);
            float4 a1 = make_float4(0.f, 0.f, 0.f, 0.f);
            if ((unsigned)iy < 56u && (unsigned)ix < 56u) {
                const float* ap = in + ((((b*56 + iy)*56 + ix)*8 + a_ic)*32 + koct*8);
                a0 = *(const float4*)(ap);
                a1 = *(const float4*)(ap + 4);
            }
            bf16x8 v;
            v[0]=f2bf(a0.x); v[1]=f2bf(a0.y); v[2]=f2bf(a0.z); v[3]=f2bf(a0.w);
            v[4]=f2bf(a1.x); v[5]=f2bf(a1.y); v[6]=f2bf(a1.z); v[7]=f2bf(a1.w);
            af[s] = v;
        }

        // ---- votes: C[16][64] = A*B, acc[nt=oc] holds N-tile nt ----
        f32x4 acc[4];
        #pragma unroll
        for (int nt = 0; nt < 4; ++nt) {
            acc[nt][0]=0.f; acc[nt][1]=0.f; acc[nt][2]=0.f; acc[nt][3]=0.f;
        }
        #pragma unroll
        for (int s = 0; s < 4; ++s) {
            #pragma unroll
            for (int nt = 0; nt < 4; ++nt) {
                bf16x8 wf = __builtin_bit_cast(bf16x8, wlds[wbase + s*256 + nt*16]);
                acc[nt] = __builtin_amdgcn_mfma_f32_16x16x32_bf16(af[s], wf, acc[nt], 0, 0, 0);
            }
        }

        // lane holds votes[ic = ich*4+q][oc][oa] for pos = posl: votes = acc[oc][q]

        // ---- dynamic routing ----
        float act[4];
        // iteration 1: logits = 0 -> route = 0.25 exactly
        #pragma unroll
        for (int oc = 0; oc < 4; ++oc) {
            float p = 0.25f*(acc[oc][0] + acc[oc][1] + acc[oc][2] + acc[oc][3]);
            p += __shfl_xor(p, 16, 64);   // join ic halves
            p += bias_v[oc];
            float sq = dpp_sum16(p * p);  // norm^2 over oa
            act[oc] = p * (sqrtf(sq) * __builtin_amdgcn_rcpf(1.f + sq));
        }
        // logits after iter 1 (start from 0): logit[q][oc] = <votes, act>
        float logit[4][4];
        #pragma unroll
        for (int q = 0; q < 4; ++q)
            #pragma unroll
            for (int oc = 0; oc < 4; ++oc)
                logit[q][oc] = dpp_sum16(acc[oc][q] * act[oc]);

        // iterations 2 and 3
        #pragma unroll
        for (int it = 1; it < 3; ++it) {
            float route[4][4];
            #pragma unroll
            for (int q = 0; q < 4; ++q) {
                float m = fmaxf(fmaxf(logit[q][0], logit[q][1]),
                                fmaxf(logit[q][2], logit[q][3]));
                float ssum = 0.f;
                #pragma unroll
                for (int oc = 0; oc < 4; ++oc) {
                    float e = __expf(logit[q][oc] - m);
                    route[q][oc] = e; ssum += e;
                }
                float inv = __builtin_amdgcn_rcpf(ssum);
                #pragma unroll
                for (int oc = 0; oc < 4; ++oc) route[q][oc] *= inv;
            }
            #pragma unroll
            for (int oc = 0; oc < 4; ++oc) {
                float p = route[0][oc]*acc[oc][0] + route[1][oc]*acc[oc][1]
                        + route[2][oc]*acc[oc][2] + route[3][oc]*acc[oc][3];
                p += __shfl_xor(p, 16, 64);
                p += bias_v[oc];
                float sq = dpp_sum16(p * p);
                act[oc] = p * (sqrtf(sq) * __builtin_amdgcn_rcpf(1.f + sq));
            }
            if (it == 1) {
                #pragma unroll
                for (int q = 0; q < 4; ++q)
                    #pragma unroll
                    for (int oc = 0; oc < 4; ++oc)
                        logit[q][oc] += dpp_sum16(acc[oc][q] * act[oc]);
            }
        }

        // ---- store activation (ich==0 lanes carry each position once) ----
        if (ich == 0) {
            const int oy = 2*y + py;
            const int ox = 2*(x0 + posl) + px;
            float* op = out + (((b*112 + oy)*112 + ox)*64 + oa);
            #pragma unroll
            for (int oc = 0; oc < 4; ++oc) op[oc*16] = act[oc];
        }
    }
}

extern "C" void kernel_launch(void* const* d_in, const int* in_sizes, int n_in,
                              void* d_out, int out_size, void* d_ws, size_t ws_size,
                              hipStream_t stream) {
    const float* in  = (const float*)d_in[0];
    const float* Wt  = (const float*)d_in[1];
    const float* bia = (const float*)d_in[2];
    float* out = (float*)d_out;
    hipLaunchKernelGGL(caps_deconv_route, dim3(1568), dim3(256), 0, stream,
                       in, Wt, bia, out);
}

// Round 3
// 86.488 us; speedup vs baseline: 1.8979x; 1.2638x over previous
//
#include <hip/hip_runtime.h>
#include <hip/hip_bf16.h>

// DeconvCapsuleLayer fused kernel, round 3.
// conv2d_transpose (votes) via bf16 MFMA + 3-iter dynamic routing.
// Round-3 changes vs round 2:
//   - ALSO compute votes^T with 16 extra swapped-operand MFMAs (MFMA pipe was
//     95% idle). T-layout: lane holds votes[pi=lane&15][oc][oa=g*4+r], g=lane>>4.
//     -> logit update (sum over oa) = 4 in-lane FMA + xor16 + xor32 per oc
//        (was dpp_sum16 x16 per update), softmax = one per-lane 4-logit pass.
//   - act/route layout bridges via tiny per-wave LDS transposes (wave-local,
//     in-order LDS pipe, no __syncthreads; all accesses <=2-way bank aliased).
//
// Conv-transpose (stride 2, K=4, SAME -> pad 1): with o = 2*y+py:
//   ky = 2*ty + (py^1), iy = y + py - ty, valid iff 0<=iy<56 (same for x).

typedef __attribute__((ext_vector_type(8))) short bf16x8;
typedef __attribute__((ext_vector_type(4))) float f32x4;

static __device__ __forceinline__ unsigned short f2bfu(float f) {
    union { __hip_bfloat16 h; unsigned short u; } cv;
    cv.h = __float2bfloat16(f);  // RNE
    return cv.u;
}
static __device__ __forceinline__ short f2bf(float f) { return (short)f2bfu(f); }

// Sum across each 16-lane row (oa group), broadcast to all 16 lanes. Pure DPP.
static __device__ __forceinline__ float dpp_sum16(float v) {
    int x;
    x = __builtin_bit_cast(int, v);
    v += __builtin_bit_cast(float, __builtin_amdgcn_mov_dpp(x, 0xB1, 0xF, 0xF, true));
    x = __builtin_bit_cast(int, v);
    v += __builtin_bit_cast(float, __builtin_amdgcn_mov_dpp(x, 0x4E, 0xF, 0xF, true));
    x = __builtin_bit_cast(int, v);
    v += __builtin_bit_cast(float, __builtin_amdgcn_mov_dpp(x, 0x141, 0xF, 0xF, true));
    x = __builtin_bit_cast(int, v);
    v += __builtin_bit_cast(float, __builtin_amdgcn_mov_dpp(x, 0x140, 0xF, 0xF, true));
    return v;
}

__global__ __launch_bounds__(256, 4)
void caps_deconv_route(const float* __restrict__ in, const float* __restrict__ Wt,
                       const float* __restrict__ bia, float* __restrict__ out) {
    const int tid  = threadIdx.x;
    const int lane = tid & 63;
    const int wid  = tid >> 6;
    const int bid  = blockIdx.x;

    // grid = 8 batches x 4 parity classes x 49 tiles
    const int tile = bid % 49;
    const int cls  = (bid / 49) & 3;
    const int b    = bid / 196;
    const int py = cls >> 1, px = cls & 1;

    // ---- stage weights (this parity class) into LDS as bf16 B-fragments ----
    __shared__ uint4 wlds[1024];        // 16 KB
    __shared__ float sw[4][192];        // per-wave transpose scratch (3 KB)
    for (int t = tid; t < 1024; t += 256) {
        const int s    = t >> 8;
        const int ko   = (t >> 6) & 3;
        const int ch   = t & 63;
        const int ky = 2*(s >> 1) + (py ^ 1);
        const int kx = 2*(s & 1)  + (px ^ 1);
        const float* wp = Wt + (((ky*4 + kx)*64 + ch)*32 + ko*8);
        const float4 w0 = *(const float4*)(wp);
        const float4 w1 = *(const float4*)(wp + 4);
        uint4 u;
        u.x = ((unsigned)f2bfu(w0.y) << 16) | f2bfu(w0.x);
        u.y = ((unsigned)f2bfu(w0.w) << 16) | f2bfu(w0.z);
        u.z = ((unsigned)f2bfu(w1.y) << 16) | f2bfu(w1.x);
        u.w = ((unsigned)f2bfu(w1.w) << 16) | f2bfu(w1.z);
        wlds[t] = u;
    }
    __syncthreads();

    const int col  = lane & 15;   // orig: oa  | T: pi
    const int koct = lane >> 4;
    const int wbase = koct*64 + col;

    const int oa   = col;
    const int posl = lane >> 5;         // orig C rows: position of the pair
    const int ich  = (lane >> 4) & 1;   // orig C rows: ic half
    const int a_pos = (lane >> 3) & 1;  // A rows: position
    const int a_ic  = lane & 7;         // A rows: ic
    const int pi   = col;               // T cols: pos*8+ic
    const int g    = koct;              // T rows: oa group (oa = g*4+r)
    const int posT = pi >> 3;

    float bias_v[4];
    #pragma unroll
    for (int oc = 0; oc < 4; ++oc) bias_v[oc] = bia[oc*16 + oa];

    float* swa = sw[wid];        // act area: [pos][oc][oa] = 128 f32
    float* swr = sw[wid] + 128;  // route area: [pi][oc] = 64 f32

    // per-lane input base: in[b][iy][ix][a_ic][koct*8..]
    const float* in_base = in + ((size_t)b*56*56*8 + a_ic)*32 + koct*8;

    int p0 = (tile*32 + wid*8) * 2;
    int y  = p0 / 56;
    int x0 = p0 - y*56;   // pairs advance by 2; 56 even -> never crosses rows

    for (int i = 0; i < 8; ++i) {
        const int yy = y + py;
        const int xx = x0 + a_pos + px;

        // ---- A fragments: A[r=pos*8+ic][k = s*32+ci] ----
        bf16x8 af[4];
        #pragma unroll
        for (int s = 0; s < 4; ++s) {
            const int ty = s >> 1, tx = s & 1;
            const int iy = yy - ty;
            const int ix = xx - tx;
            float4 a0 = make_float4(0.f, 0.f, 0.f, 0.f);
            float4 a1 = make_float4(0.f, 0.f, 0.f, 0.f);
            if ((unsigned)iy < 56u && (unsigned)ix < 56u) {
                const float* ap = in_base + (size_t)(iy*56 + ix) * 256;
                a0 = *(const float4*)(ap);
                a1 = *(const float4*)(ap + 4);
            }
            bf16x8 v;
            v[0]=f2bf(a0.x); v[1]=f2bf(a0.y); v[2]=f2bf(a0.z); v[3]=f2bf(a0.w);
            v[4]=f2bf(a1.x); v[5]=f2bf(a1.y); v[6]=f2bf(a1.z); v[7]=f2bf(a1.w);
            af[s] = v;
        }

        // ---- votes both ways: acc = A*B (orig), accT = B^T*A^T (transposed) ----
        f32x4 acc[4], accT[4];
        #pragma unroll
        for (int nt = 0; nt < 4; ++nt) {
            acc[nt][0]=0.f; acc[nt][1]=0.f; acc[nt][2]=0.f; acc[nt][3]=0.f;
            accT[nt][0]=0.f; accT[nt][1]=0.f; accT[nt][2]=0.f; accT[nt][3]=0.f;
        }
        #pragma unroll
        for (int s = 0; s < 4; ++s) {
            #pragma unroll
            for (int nt = 0; nt < 4; ++nt) {
                bf16x8 wf = __builtin_bit_cast(bf16x8, wlds[wbase + s*256 + nt*16]);
                acc[nt]  = __builtin_amdgcn_mfma_f32_16x16x32_bf16(af[s], wf, acc[nt], 0, 0, 0);
                accT[nt] = __builtin_amdgcn_mfma_f32_16x16x32_bf16(wf, af[s], accT[nt], 0, 0, 0);
            }
        }
        // orig: lane(pos=posl,ich,oa): acc[oc][q] = votes[ic=ich*4+q][oc][oa]
        // T:    lane(pi,g):          accT[oc][r] = votes[pi][oc][oa=g*4+r]

        // ---- routing iteration 1 (logits=0 -> route=0.25 exactly) ----
        float act[4];
        #pragma unroll
        for (int oc = 0; oc < 4; ++oc) {
            float p = 0.25f*(acc[oc][0] + acc[oc][1] + acc[oc][2] + acc[oc][3]);
            p += __shfl_xor(p, 16, 64);   // join ic halves
            p += bias_v[oc];
            float sq = dpp_sum16(p * p);
            act[oc] = p * (sqrtf(sq) * __builtin_amdgcn_rcpf(1.f + sq));
        }

        // act -> T layout via LDS
        if (ich == 0) {
            #pragma unroll
            for (int oc = 0; oc < 4; ++oc) swa[posl*64 + oc*16 + oa] = act[oc];
        }
        asm volatile("s_waitcnt lgkmcnt(0)" ::: "memory");
        float logit[4];
        #pragma unroll
        for (int oc = 0; oc < 4; ++oc) {
            float4 at = *(const float4*)&swa[posT*64 + oc*16 + g*4];
            float part = accT[oc][0]*at.x + accT[oc][1]*at.y
                       + accT[oc][2]*at.z + accT[oc][3]*at.w;
            part += __shfl_xor(part, 16, 64);
            part += __shfl_xor(part, 32, 64);
            logit[oc] = part;   // logit for this lane's pi, broadcast over g
        }

        // ---- iterations 2 and 3 ----
        #pragma unroll
        for (int it = 1; it < 3; ++it) {
            // per-lane softmax over oc (lane owns pi)
            float m = fmaxf(fmaxf(logit[0], logit[1]), fmaxf(logit[2], logit[3]));
            float e0 = __expf(logit[0]-m), e1 = __expf(logit[1]-m);
            float e2 = __expf(logit[2]-m), e3 = __expf(logit[3]-m);
            float inv = __builtin_amdgcn_rcpf(e0+e1+e2+e3);
            // route -> orig layout via LDS
            if (lane < 16) {
                float4 rt = make_float4(e0*inv, e1*inv, e2*inv, e3*inv);
                *(float4*)&swr[pi*4] = rt;
            }
            asm volatile("s_waitcnt lgkmcnt(0)" ::: "memory");
            const int rb = (posl*8 + ich*4) * 4;
            float4 rq0 = *(const float4*)&swr[rb];
            float4 rq1 = *(const float4*)&swr[rb + 4];
            float4 rq2 = *(const float4*)&swr[rb + 8];
            float4 rq3 = *(const float4*)&swr[rb + 12];

            float p0c = rq0.x*acc[0][0] + rq1.x*acc[0][1] + rq2.x*acc[0][2] + rq3.x*acc[0][3];
            float p1c = rq0.y*acc[1][0] + rq1.y*acc[1][1] + rq2.y*acc[1][2] + rq3.y*acc[1][3];
            float p2c = rq0.z*acc[2][0] + rq1.z*acc[2][1] + rq2.z*acc[2][2] + rq3.z*acc[2][3];
            float p3c = rq0.w*acc[3][0] + rq1.w*acc[3][1] + rq2.w*acc[3][2] + rq3.w*acc[3][3];
            float pr[4] = {p0c, p1c, p2c, p3c};
            #pragma unroll
            for (int oc = 0; oc < 4; ++oc) {
                float p = pr[oc];
                p += __shfl_xor(p, 16, 64);
                p += bias_v[oc];
                float sq = dpp_sum16(p * p);
                act[oc] = p * (sqrtf(sq) * __builtin_amdgcn_rcpf(1.f + sq));
            }
            if (it == 1) {
                if (ich == 0) {
                    #pragma unroll
                    for (int oc = 0; oc < 4; ++oc) swa[posl*64 + oc*16 + oa] = act[oc];
                }
                asm volatile("s_waitcnt lgkmcnt(0)" ::: "memory");
                #pragma unroll
                for (int oc = 0; oc < 4; ++oc) {
                    float4 at = *(const float4*)&swa[posT*64 + oc*16 + g*4];
                    float part = accT[oc][0]*at.x + accT[oc][1]*at.y
                               + accT[oc][2]*at.z + accT[oc][3]*at.w;
                    part += __shfl_xor(part, 16, 64);
                    part += __shfl_xor(part, 32, 64);
                    logit[oc] += part;
                }
            }
        }

        // ---- store activation (ich==0 lanes carry each position once) ----
        if (ich == 0) {
            const int oy = 2*y + py;
            const int ox = 2*(x0 + posl) + px;
            float* op = out + ((((size_t)b*112 + oy)*112 + ox)*64 + oa);
            #pragma unroll
            for (int oc = 0; oc < 4; ++oc) op[oc*16] = act[oc];
        }

        x0 += 2;
        if (x0 >= 56) { x0 -= 56; ++y; }
    }
}

extern "C" void kernel_launch(void* const* d_in, const int* in_sizes, int n_in,
                              void* d_out, int out_size, void* d_ws, size_t ws_size,
                              hipStream_t stream) {
    const float* in  = (const float*)d_in[0];
    const float* Wt  = (const float*)d_in[1];
    const float* bia = (const float*)d_in[2];
    float* out = (float*)d_out;
    hipLaunchKernelGGL(caps_deconv_route, dim3(1568), dim3(256), 0, stream,
                       in, Wt, bia, out);
}